// Round 9
// baseline (389.276 us; speedup 1.0000x reference)
//
#include <hip/hip_runtime.h>
#include <hip/hip_bf16.h>

#define N_GRAPHS 64
#define IN_FEATS 64
#define HIDDEN 32
#define OUT_DIM 2

#define NB 512        // dst-range buckets
#define PCH 8192      // edges per partition block (LDS stage = 32 KB packed)
#define GCH 256       // nodes per k_gsum2 chunk

__device__ __forceinline__ float bf2f(unsigned short u) {
    unsigned int x = ((unsigned int)u) << 16;
    float f;
    __builtin_memcpy(&f, &x, 4);
    return f;
}

__device__ __forceinline__ unsigned short f2bf(float f) {
    __hip_bfloat16 h = __float2bfloat16(f);   // RNE
    unsigned short u;
    __builtin_memcpy(&u, &h, 2);
    return u;
}

// ---------------- layer 1 linear (node-parallel) ----------------

// t = node_feats(f32 [N,64]) @ W1(f32 [64,32]) -> bf16 [N,32] (bias deferred)
__global__ void k_lin1(const float* __restrict__ nf,
                       const float* __restrict__ W,
                       unsigned int* __restrict__ t, int n) {
    __shared__ float w[IN_FEATS * HIDDEN];
    for (int i = threadIdx.x; i < IN_FEATS * HIDDEN; i += blockDim.x)
        w[i] = W[i];
    __syncthreads();
    int row = blockIdx.x * blockDim.x + threadIdx.x;
    if (row >= n) return;

    float a[IN_FEATS];
    const float4* r4 = reinterpret_cast<const float4*>(nf + (long long)row * IN_FEATS);
    #pragma unroll
    for (int v = 0; v < IN_FEATS / 4; v++) {
        float4 q = r4[v];
        a[v * 4 + 0] = q.x; a[v * 4 + 1] = q.y; a[v * 4 + 2] = q.z; a[v * 4 + 3] = q.w;
    }
    float acc[HIDDEN];
    #pragma unroll
    for (int f = 0; f < HIDDEN; f++) acc[f] = 0.f;
    for (int k = 0; k < IN_FEATS; k++) {
        float av = a[k];
        #pragma unroll
        for (int f = 0; f < HIDDEN; f++) acc[f] += av * w[k * HIDDEN + f];
    }
    unsigned int packed[HIDDEN / 2];
    #pragma unroll
    for (int f = 0; f < HIDDEN / 2; f++)
        packed[f] = (unsigned int)f2bf(acc[2 * f]) | ((unsigned int)f2bf(acc[2 * f + 1]) << 16);
    uint4* o = reinterpret_cast<uint4*>(t + (long long)row * 16);
    #pragma unroll
    for (int v = 0; v < 4; v++)
        o[v] = make_uint4(packed[v * 4], packed[v * 4 + 1], packed[v * 4 + 2], packed[v * 4 + 3]);
}

// ---------------- fused gather + linear (8 lanes/node, per-wave tiles) ----------------

// 8 lanes per node (lane owns feats 4l..4l+3). Gather bf16 rows, +b, @W(32x32) -> bf16 out.
// No __syncthreads in hot path: rows tile is per-wave (same-wave LDS write->read).
__global__ __launch_bounds__(256) void k_gather_lin2(const uint2* __restrict__ tin,
                                                     const int* __restrict__ csr,
                                                     const int* __restrict__ ptr,
                                                     const float* __restrict__ b,
                                                     const float* __restrict__ W,
                                                     uint2* __restrict__ tout,
                                                     int n) {
    __shared__ float w[HIDDEN * HIDDEN];      // row-major W[k][f]
    __shared__ float bs[HIDDEN];
    __shared__ float rows[4][8][HIDDEN];      // [wave][group][feat]
    int tid = threadIdx.x;
    for (int i = tid; i < HIDDEN * HIDDEN; i += 256) w[i] = W[i];
    if (tid < HIDDEN) bs[tid] = b[tid];
    __syncthreads();

    int wv = tid >> 6;        // wave 0..3
    int g = (tid >> 3) & 7;   // group (node) within wave
    int l = tid & 7;          // lane within group
    int node = blockIdx.x * 32 + wv * 8 + g;
    bool act = node < n;

    float a0 = 0.f, a1 = 0.f, a2 = 0.f, a3 = 0.f;
    int start = 0, end = 0;
    if (act) {
        start = node ? ptr[node - 1] : 0;
        end = ptr[node];
    }
    for (int j = start; j < end; j += 8) {
        int c = (j + l < end) ? csr[j + l] : 0;   // coalesced chunk of 8 edge srcs
        #pragma unroll
        for (int e = 0; e < 8; e++) {
            if (j + e < end) {                    // group-uniform guard
                int s = __shfl(c, e, 8);
                uint2 u = tin[s * 8 + l];
                a0 += bf2f((unsigned short)(u.x & 0xffffu));
                a1 += bf2f((unsigned short)(u.x >> 16));
                a2 += bf2f((unsigned short)(u.y & 0xffffu));
                a3 += bf2f((unsigned short)(u.y >> 16));
            }
        }
    }
    if (act) {
        float4 bb = *reinterpret_cast<const float4*>(bs + 4 * l);
        float4* rw = reinterpret_cast<float4*>(&rows[wv][g][4 * l]);
        *rw = make_float4(a0 + bb.x, a1 + bb.y, a2 + bb.z, a3 + bb.w);
    }
    __builtin_amdgcn_wave_barrier();   // order LDS write before reads (same wave)
    if (!act) return;

    float c0 = 0.f, c1 = 0.f, c2 = 0.f, c3 = 0.f;
    #pragma unroll
    for (int k = 0; k < HIDDEN; k++) {
        float rk = rows[wv][g][k];                                  // broadcast
        float4 wk = *reinterpret_cast<const float4*>(w + k * HIDDEN + 4 * l);  // b128, conflict-free
        c0 += rk * wk.x; c1 += rk * wk.y; c2 += rk * wk.z; c3 += rk * wk.w;
    }
    uint2 o;
    o.x = (unsigned int)f2bf(c0) | ((unsigned int)f2bf(c1) << 16);
    o.y = (unsigned int)f2bf(c2) | ((unsigned int)f2bf(c3) << 16);
    tout[node * 8 + l] = o;
}

// 8 lanes per node: gather row, add b2, @W3 (32x2) via shfl reduce -> t3 f32 [N,2]
__global__ __launch_bounds__(256) void k_gather_lin3(const uint2* __restrict__ tin,
                                                     const int* __restrict__ csr,
                                                     const int* __restrict__ ptr,
                                                     const float* __restrict__ b,
                                                     const float* __restrict__ W,
                                                     float* __restrict__ t3,
                                                     int n) {
    __shared__ float w[HIDDEN * OUT_DIM];
    __shared__ float bs[HIDDEN];
    int tid = threadIdx.x;
    if (tid < HIDDEN * OUT_DIM) w[tid] = W[tid];
    if (tid < HIDDEN) bs[tid] = b[tid];
    __syncthreads();

    int g = tid >> 3;
    int l = tid & 7;
    int node = blockIdx.x * 32 + g;
    if (node >= n) return;

    int start = node ? ptr[node - 1] : 0;
    int end = ptr[node];
    float a0 = 0.f, a1 = 0.f, a2 = 0.f, a3 = 0.f;
    for (int j = start; j < end; j += 8) {
        int c = (j + l < end) ? csr[j + l] : 0;
        #pragma unroll
        for (int e = 0; e < 8; e++) {
            if (j + e < end) {
                int s = __shfl(c, e, 8);
                uint2 u = tin[s * 8 + l];
                a0 += bf2f((unsigned short)(u.x & 0xffffu));
                a1 += bf2f((unsigned short)(u.x >> 16));
                a2 += bf2f((unsigned short)(u.y & 0xffffu));
                a3 += bf2f((unsigned short)(u.y >> 16));
            }
        }
    }
    float4 bb = *reinterpret_cast<const float4*>(bs + 4 * l);
    float r0 = a0 + bb.x, r1 = a1 + bb.y, r2 = a2 + bb.z, r3 = a3 + bb.w;
    int k0 = 4 * l;
    float p0 = r0 * w[(k0 + 0) * 2] + r1 * w[(k0 + 1) * 2] + r2 * w[(k0 + 2) * 2] + r3 * w[(k0 + 3) * 2];
    float p1 = r0 * w[(k0 + 0) * 2 + 1] + r1 * w[(k0 + 1) * 2 + 1] + r2 * w[(k0 + 2) * 2 + 1] + r3 * w[(k0 + 3) * 2 + 1];
    #pragma unroll
    for (int off = 1; off < 8; off <<= 1) {
        p0 += __shfl_xor(p0, off, 8);
        p1 += __shfl_xor(p1, off, 8);
    }
    if (l == 0) {
        float2* o = reinterpret_cast<float2*>(t3 + (long long)node * 2);
        *o = make_float2(p0, p1);
    }
}

// ---------------- CSR build: bucket partition + local counting sort ----------------

__global__ __launch_bounds__(256) void k_hist(const int* __restrict__ dst,
                                              int* __restrict__ gcount,
                                              int E, int nb_sz) {
    __shared__ int lc[NB];
    for (int k = threadIdx.x; k < NB; k += 256) lc[k] = 0;
    __syncthreads();
    int stride = gridDim.x * 256;
    for (int i = blockIdx.x * 256 + threadIdx.x; i < E; i += stride)
        atomicAdd(&lc[dst[i] / nb_sz], 1);
    __syncthreads();
    for (int k = threadIdx.x; k < NB; k += 256)
        if (lc[k]) atomicAdd(&gcount[k], lc[k]);
}

__global__ __launch_bounds__(256) void k_scan512(const int* __restrict__ gcount,
                                                 int* __restrict__ gbase,
                                                 int* __restrict__ gcur, int E) {
    __shared__ int sA[NB], sB[NB];
    int tid = threadIdx.x;
    int c0 = gcount[tid], c1 = gcount[tid + 256];
    sA[tid] = c0; sA[tid + 256] = c1;
    __syncthreads();
    int* a = sA; int* bb = sB;
    for (int off = 1; off < NB; off <<= 1) {
        for (int k = tid; k < NB; k += 256) {
            int v = a[k];
            if (k >= off) v += a[k - off];
            bb[k] = v;
        }
        __syncthreads();
        int* t_ = a; a = bb; bb = t_;
    }
    int e0 = a[tid] - c0, e1 = a[tid + 256] - c1;
    gbase[tid] = e0;       gbase[tid + 256] = e1;
    gcur[tid] = e0;        gcur[tid + 256] = e1;
    if (tid == 0) gbase[NB] = E;
}

// packed pair: (src << 8) | (dst - bucket_base); nb_sz<=256 so local dst fits 8 bits
__global__ __launch_bounds__(256) void k_partition(const int* __restrict__ src,
                                                   const int* __restrict__ dst,
                                                   int* __restrict__ gcur,
                                                   unsigned int* __restrict__ pairs,
                                                   int E, int nb_sz) {
    __shared__ unsigned int stage[PCH];
    __shared__ int sA[NB], sB[NB], ofs[NB + 1], cur[NB], rbase[NB];
    int tid = threadIdx.x;
    int e0 = blockIdx.x * PCH;
    int m = E - e0; if (m > PCH) m = PCH;

    for (int k = tid; k < NB; k += 256) sA[k] = 0;
    __syncthreads();
    for (int i = tid; i < m; i += 256)
        atomicAdd(&sA[dst[e0 + i] / nb_sz], 1);
    __syncthreads();
    int c0 = sA[tid], c1 = sA[tid + 256];
    int* a = sA; int* bb = sB;
    for (int off = 1; off < NB; off <<= 1) {
        for (int k = tid; k < NB; k += 256) {
            int v = a[k];
            if (k >= off) v += a[k - off];
            bb[k] = v;
        }
        __syncthreads();
        int* t_ = a; a = bb; bb = t_;
    }
    int x0 = a[tid] - c0, x1 = a[tid + 256] - c1;
    ofs[tid] = x0;       ofs[tid + 256] = x1;
    cur[tid] = x0;       cur[tid + 256] = x1;
    if (tid == 0) ofs[NB] = m;
    __syncthreads();
    for (int i = tid; i < m; i += 256) {
        int d = dst[e0 + i];
        int s = src[e0 + i];
        int b = d / nb_sz;
        int p = atomicAdd(&cur[b], 1);
        stage[p] = ((unsigned)s << 8) | (unsigned)(d - b * nb_sz);
    }
    __syncthreads();
    for (int k = tid; k < NB; k += 256) {
        int cnt = ofs[k + 1] - ofs[k];
        rbase[k] = cnt > 0 ? atomicAdd(&gcur[k], cnt) : 0;
    }
    __syncthreads();
    for (int i = tid; i < m; i += 256) {
        int lo = 0, hi = NB;
        while (hi - lo > 1) {
            int mid = (lo + hi) >> 1;
            if (ofs[mid] <= i) lo = mid; else hi = mid;
        }
        pairs[rbase[lo] + (i - ofs[lo])] = stage[i];
    }
}

// per-bucket counting sort -> csr (src only) + ptr (per-node END offsets)
__global__ __launch_bounds__(256) void k_csr_local(const unsigned int* __restrict__ pairs,
                                                   const int* __restrict__ gbase,
                                                   int* __restrict__ csr,
                                                   int* __restrict__ ptr,
                                                   int N, int nb_sz) {
    int b = blockIdx.x;
    int n0 = b * nb_sz;
    if (n0 >= N) return;
    int n1 = n0 + nb_sz; if (n1 > N) n1 = N;
    int nn = n1 - n0;

    __shared__ int cnt[256], scn[256], cur[256];
    int tid = threadIdx.x;
    cnt[tid] = 0;
    __syncthreads();
    int s = gbase[b], e = gbase[b + 1];
    for (int i = s + tid; i < e; i += 256)
        atomicAdd(&cnt[pairs[i] & 0xFFu], 1);
    __syncthreads();
    int c = cnt[tid];
    scn[tid] = c;
    __syncthreads();
    for (int off = 1; off < 256; off <<= 1) {
        int mine = scn[tid];
        int add = (tid >= off) ? scn[tid - off] : 0;
        __syncthreads();
        scn[tid] = mine + add;
        __syncthreads();
    }
    cur[tid] = scn[tid] - c;                      // exclusive prefix
    if (tid < nn) ptr[n0 + tid] = s + scn[tid];   // end offset
    __syncthreads();
    for (int i = s + tid; i < e; i += 256) {
        unsigned int p = pairs[i];
        int pos = atomicAdd(&cur[p & 0xFFu], 1);
        csr[s + pos] = (int)(p >> 8);
    }
}

// ---------------- final gather (2 f32 feats) + bias -> d_out ----------------

__global__ void k_gather2_out(const float* __restrict__ t3,
                              const int* __restrict__ csr,
                              const int* __restrict__ ptr,
                              const float* __restrict__ b3,
                              float* __restrict__ out, int n) {
    int node = blockIdx.x * blockDim.x + threadIdx.x;
    if (node >= n) return;
    int start = node ? ptr[node - 1] : 0;
    int end = ptr[node];
    float a0 = 0.f, a1 = 0.f;
    int j = start;
    for (; j + 1 < end; j += 2) {
        int s0 = csr[j], s1 = csr[j + 1];
        float2 v0 = *reinterpret_cast<const float2*>(t3 + (long long)s0 * 2);
        float2 v1 = *reinterpret_cast<const float2*>(t3 + (long long)s1 * 2);
        a0 += v0.x + v1.x;
        a1 += v0.y + v1.y;
    }
    if (j < end) {
        float2 v = *reinterpret_cast<const float2*>(t3 + (long long)csr[j] * 2);
        a0 += v.x; a1 += v.y;
    }
    float2* o = reinterpret_cast<float2*>(out + (long long)node * 2);
    *o = make_float2(a0 + b3[0], a1 + b3[1]);
}

// ---------------- init + graph embedding + prediction ----------------

// zero ge/gcount/done, compute graph start bounds (single block)
__global__ __launch_bounds__(256) void k_init(const int* __restrict__ gids, int n,
                                              int* __restrict__ gstart,
                                              float* __restrict__ ge,
                                              int* __restrict__ gcount,
                                              int* __restrict__ done) {
    int tid = threadIdx.x;
    for (int i = tid; i < N_GRAPHS * IN_FEATS; i += 256) ge[i] = 0.f;
    for (int i = tid; i < NB; i += 256) gcount[i] = 0;
    if (tid == 0) *done = 0;
    if (tid <= N_GRAPHS) {
        int g = tid;
        int lo = 0, hi = n;
        while (lo < hi) {
            int mid = (lo + hi) >> 1;
            if (gids[mid] < g) lo = mid + 1; else hi = mid;
        }
        gstart[g] = lo;
    }
}

// chunk-parallel per-graph SUM; last block computes prediction (fused k_pred)
__global__ __launch_bounds__(256) void k_gsum2(const float* __restrict__ nf,
                                               const int* __restrict__ gids,
                                               const int* __restrict__ gstart,
                                               float* __restrict__ ge, int N,
                                               int nblocks, int* __restrict__ done,
                                               const float* __restrict__ Wl,
                                               const float* __restrict__ bl,
                                               float* __restrict__ out) {
    int c0 = blockIdx.x * GCH;
    int c1 = c0 + GCH; if (c1 > N) c1 = N;
    int tid = threadIdx.x;
    int ng = tid >> 4;    // node group 0..15
    int f4 = tid & 15;    // float4 column

    if (c0 < N) {
        int gfirst = gids[c0];
        int glast  = gids[c1 - 1];
        __shared__ float4 red[256];
        for (int g = gfirst; g <= glast; g++) {
            int s = gstart[g];     if (s < c0) s = c0;
            int e = gstart[g + 1]; if (e > c1) e = c1;
            float4 acc = make_float4(0.f, 0.f, 0.f, 0.f);
            for (int i = s + ng; i < e; i += 16) {
                float4 v = *reinterpret_cast<const float4*>(nf + (long long)i * IN_FEATS + f4 * 4);
                acc.x += v.x; acc.y += v.y; acc.z += v.z; acc.w += v.w;
            }
            red[tid] = acc;
            __syncthreads();
            for (int off = 8; off > 0; off >>= 1) {
                if (ng < off) {
                    float4 o = red[(ng + off) * 16 + f4];
                    float4 m = red[tid];
                    m.x += o.x; m.y += o.y; m.z += o.z; m.w += o.w;
                    red[tid] = m;
                }
                __syncthreads();
            }
            if (ng == 0 && e > s) {
                float4 m = red[f4];
                atomicAdd(&ge[g * IN_FEATS + f4 * 4 + 0], m.x);
                atomicAdd(&ge[g * IN_FEATS + f4 * 4 + 1], m.y);
                atomicAdd(&ge[g * IN_FEATS + f4 * 4 + 2], m.z);
                atomicAdd(&ge[g * IN_FEATS + f4 * 4 + 3], m.w);
            }
            __syncthreads();
        }
    }

    // last finishing block computes the prediction
    __threadfence();
    __shared__ int isLast;
    if (tid == 0) isLast = (atomicAdd(done, 1) == nblocks - 1) ? 1 : 0;
    __syncthreads();
    if (isLast) {
        __threadfence();
        int g = tid;
        if (g < N_GRAPHS) {
            float cnt = (float)(gstart[g + 1] - gstart[g]);
            float inv = 1.f / fmaxf(cnt, 1.0f);
            float acc = 0.f;
            for (int k = 0; k < IN_FEATS; k++)
                acc += ge[g * IN_FEATS + k] * Wl[k];
            acc = acc * inv + bl[0];
            out[g] = 1.f / (1.f + expf(-acc));
        }
    }
}

extern "C" void kernel_launch(void* const* d_in, const int* in_sizes, int n_in,
                              void* d_out, int out_size, void* d_ws, size_t ws_size,
                              hipStream_t stream) {
    const float* nf = (const float*)d_in[0];   // node_feats f32 [N,64]
    const float* W1 = (const float*)d_in[2];   // [64,32]
    const float* b1 = (const float*)d_in[3];   // [32]
    const float* W2 = (const float*)d_in[4];   // [32,32]
    const float* b2 = (const float*)d_in[5];   // [32]
    const float* W3 = (const float*)d_in[6];   // [32,2]
    const float* b3 = (const float*)d_in[7];   // [2]
    const float* Wl = (const float*)d_in[8];   // [64,1]
    const float* bl = (const float*)d_in[9];   // [1]
    const int* src  = (const int*)d_in[10];
    const int* dst  = (const int*)d_in[11];
    const int* gids = (const int*)d_in[12];

    const int N = in_sizes[0] / IN_FEATS;     // 100000
    const int E = in_sizes[10];               // 1600000
    const int nb_sz = (N + NB - 1) / NB;      // 196 (<=256 required for packing)

    float* out = (float*)d_out;

    // workspace layout:
    unsigned int* tA = (unsigned int*)d_ws;                // bf16 table A [N,32] (6.4MB)
    unsigned int* tB = tA + (size_t)N * 16;                // bf16 table B [N,32] (6.4MB)
    float* t3    = (float*)(tB + (size_t)N * 16);          // [N,2] f32 (0.8MB)
    unsigned int* pairs = (unsigned int*)(t3 + (size_t)N * OUT_DIM); // [E] packed (6.4MB)
    int* csr     = (int*)(pairs + E);                      // [E] (6.4MB)
    int* ptr     = csr + E;                                // [N]
    int* gcount  = ptr + N;                                // [NB]
    int* gbase   = gcount + NB;                            // [NB+1]
    int* gcur    = gbase + NB + 1;                         // [NB]
    float* ge    = (float*)(gcur + NB);                    // [64,64]
    int* gstart  = (int*)(ge + N_GRAPHS * IN_FEATS);       // [65]
    int* done    = gstart + N_GRAPHS + 1;                  // [1]

    const int TB = 256;
    int nodeBlocks = (N + TB - 1) / TB;
    int partBlocks = (E + PCH - 1) / PCH;
    int fusedBlocks = (N + 31) / 32;
    int gsumBlocks = (N + GCH - 1) / GCH;

    // ---- init (zero ge/gcount/done + graph bounds) ----
    k_init<<<1, TB, 0, stream>>>(gids, N, gstart, ge, gcount, done);

    // ---- graph embedding + prediction (fused last-block pred) ----
    k_gsum2<<<gsumBlocks, TB, 0, stream>>>(nf, gids, gstart, ge, N,
                                           gsumBlocks, done, Wl, bl, out);

    // ---- CSR build (once, reused for all 3 layers) ----
    k_hist<<<256, TB, 0, stream>>>(dst, gcount, E, nb_sz);
    k_scan512<<<1, TB, 0, stream>>>(gcount, gbase, gcur, E);
    k_partition<<<partBlocks, TB, 0, stream>>>(src, dst, gcur, pairs, E, nb_sz);
    k_csr_local<<<NB, TB, 0, stream>>>(pairs, gbase, csr, ptr, N, nb_sz);

    // ---- GCN chain (fused gather+linear at layer boundaries) ----
    k_lin1<<<nodeBlocks, TB, 0, stream>>>(nf, W1, tA, N);
    k_gather_lin2<<<fusedBlocks, TB, 0, stream>>>((const uint2*)tA, csr, ptr, b1, W2, (uint2*)tB, N);
    k_gather_lin3<<<fusedBlocks, TB, 0, stream>>>((const uint2*)tB, csr, ptr, b2, W3, t3, N);
    k_gather2_out<<<nodeBlocks, TB, 0, stream>>>(t3, csr, ptr, b3, out + N_GRAPHS, N);
}